// Round 11
// baseline (100.069 us; speedup 1.0000x reference)
//
#include <hip/hip_runtime.h>
#include <math.h>

// CorrNet fused MFMA-f16 kernel, v8: 32KB LDS half-chunk staging for occupancy.
// M=128, K=64, T=64, N=131072, D_IN=320.
// 256-thread blocks (4 waves x 32 samples = 128 samples/block). LDS = 32KB
// -> up to 5 blocks/CU (vs R9's 56KB -> 1-2). Weights staged in half-chunks:
// resblock: [w0-colhalf 24KB | w1 8KB], head: [w0o 16KB | tp0 8KB] then
// [w1o 8KB | tp1 8KB]. State in registers (phi-permuted packed f16
// B-fragments, in-lane cvt_pkrtz updates).

typedef _Float16 f16;
typedef _Float16 f16x8 __attribute__((ext_vector_type(8)));
typedef __fp16   fp16x2 __attribute__((ext_vector_type(2)));
typedef float    f32x4 __attribute__((ext_vector_type(4)));
typedef int      i32x4 __attribute__((ext_vector_type(4)));

#define MFMA16(a, b, c) __builtin_amdgcn_mfma_f32_16x16x32_f16(a, b, c, 0, 0, 0)

constexpr float INV_SQRT_M = 0.08838834764831845f;   // 1/sqrt(128)
constexpr float INV_SQRT_K = 0.125f;                 // 1/sqrt(64)
constexpr float INV_SQRT_3 = 0.57735026918962576f;
constexpr float TP_NORM    = 0.011048543456039806f;  // 1/sqrt(2*64*64)

// packed-weight segment offsets in f16 units (base = d_ws + 16 bytes)
// w01: frags ordered [half][ks][njh] so each column-half is contiguous 12288.
#define OFF_W01 0
#define OFF_W11 24576
#define OFF_W02 28672
#define OFF_W12 53248
#define OFF_W0O 57344
#define OFF_TP0 65536
#define OFF_W1O 69632
#define OFF_TP1 73728
#define PACK_UNITS 9728   // total f16x8 units

#define LDS_W1 12288      // w1 location during resblock (f16 units)
#define NTHR 256

// ---------------------------------------------------------------------------
__global__ void init_consts_kernel(float* __restrict__ ws) {
    __shared__ double red[256];
    const int t = threadIdx.x;
    double acc_s = 0.0, acc_r = 0.0;
    for (int i = t; i <= 20000; i += 256) {
        const double z = -8.0 + (16.0 * (double)i) / 20000.0;
        const double pdf = exp(-0.5 * z * z) / 2.5066282746310002;
        const double sil = z / (1.0 + exp(-z));
        const double wgt = (i == 0 || i == 20000) ? 0.5 : 1.0;
        acc_s += wgt * sil * sil * pdf;
        if (z > 0.0) acc_r += wgt * z * z * pdf;
    }
    red[t] = acc_s;
    __syncthreads();
    for (int o = 128; o > 0; o >>= 1) { if (t < o) red[t] += red[t + o]; __syncthreads(); }
    const double tot_s = red[0];
    __syncthreads();
    red[t] = acc_r;
    __syncthreads();
    for (int o = 128; o > 0; o >>= 1) { if (t < o) red[t] += red[t + o]; __syncthreads(); }
    if (t == 0) {
        const double dz = 16.0 / 20000.0;
        ws[0] = (float)(1.0 / sqrt(tot_s * dz));
        ws[1] = (float)(1.0 / sqrt(red[0] * dz));
    }
}

// ---------------------------------------------------------------------------
// Pack weights fp32 -> f16 A-fragments of W^T, phi-permuted k-rows, scales
// folded. For 192-col matrices the fragment order is [half][ks][njh]
// (nj = half*6 + njh) so each column-half is a contiguous 24KB block.
// Fragment lane l, elem e holds
//   scale * W[kstep*32 + 16*(e>>2) + 4*(l>>4) + (e&3)][nj*16 + (l&15)]
// ---------------------------------------------------------------------------
__global__ void pack_weights(const float* __restrict__ w01, const float* __restrict__ w11,
                             const float* __restrict__ w02, const float* __restrict__ w12,
                             const float* __restrict__ w0o, const float* __restrict__ w1o,
                             const float* __restrict__ tp0, const float* __restrict__ tp1,
                             f16* __restrict__ dst) {
    int u = blockIdx.x * 256 + threadIdx.x;
    if (u >= PACK_UNITS) return;
    const float* src; int NC, base, lu = u; float sc;
    if      (lu < 3072) {            src = w01; NC = 192; base = OFF_W01; sc = INV_SQRT_M; }
    else if (lu < 3584) { lu -= 3072; src = w11; NC = 64;  base = OFF_W11; sc = INV_SQRT_K; }
    else if (lu < 6656) { lu -= 3584; src = w02; NC = 192; base = OFF_W02; sc = INV_SQRT_M; }
    else if (lu < 7168) { lu -= 6656; src = w12; NC = 64;  base = OFF_W12; sc = INV_SQRT_K; }
    else if (lu < 8192) { lu -= 7168; src = w0o; NC = 64;  base = OFF_W0O; sc = INV_SQRT_M; }
    else if (lu < 8704) { lu -= 8192; src = tp0; NC = 64;  base = OFF_TP0; sc = 1.0f; }
    else if (lu < 9216) { lu -= 8704; src = w1o; NC = 64;  base = OFF_W1O; sc = INV_SQRT_K; }
    else                { lu -= 9216; src = tp1; NC = 64;  base = OFF_TP1; sc = INV_SQRT_3; }
    const int lane = lu & 63;
    const int frag = lu >> 6;
    int kstep, nj;
    if (NC == 192) {   // frag = half*24 + ks*6 + njh
        const int half = frag / 24;
        const int rem  = frag - half * 24;
        kstep = rem / 6;
        nj    = half * 6 + (rem - kstep * 6);
    } else {           // frag = ks*4 + nj
        kstep = frag >> 2;
        nj    = frag & 3;
    }
    const int gl  = lane >> 4;
    const int col = nj * 16 + (lane & 15);
    f16 tmp[8];
    #pragma unroll
    for (int e = 0; e < 8; ++e) {
        const int row = kstep * 32 + ((e >> 2) << 4) + (gl << 2) + (e & 3);  // phi
        tmp[e] = (f16)(src[(size_t)row * NC + col] * sc);
    }
    *(f16x8*)&dst[(size_t)(base) + (size_t)lu * 8] = *(f16x8*)tmp;
}

// ---------------------------------------------------------------------------
__device__ __forceinline__ int pk2i(float a, float b) {
    union { fp16x2 h; int i; } u;
    u.h = __builtin_amdgcn_cvt_pkrtz(a, b);
    return u.i;
}

__device__ __forceinline__ f16x8 packB(f32x4 t0, f32x4 t1) {
    union { i32x4 i; f16x8 v; } u;
    u.i[0] = pk2i(t0[0], t0[1]);
    u.i[1] = pk2i(t0[2], t0[3]);
    u.i[2] = pk2i(t1[0], t1[1]);
    u.i[3] = pk2i(t1[2], t1[3]);
    return u.v;
}

union Frag { f16x8 v; fp16x2 h2[4]; };

// ---------------------------------------------------------------------------
// One ys half: 6 column-tiles (nj = njbase..njbase+5) from the staged w0 half.
// nj<8 -> silu update into xsS; nj>=8 -> gate.
// ---------------------------------------------------------------------------
__device__ __forceinline__ void ys_half(
    Frag (&xsS)[2][4], const f16x8 (&xsB)[2][4], float (&gate)[2][4][4],
    const f16* lds, const float* __restrict__ b0, int njbase,
    float invCS, float invCR, int l, int g)
{
    #pragma unroll
    for (int njh = 0; njh < 6; ++njh) {
        const int nj = njbase + njh;
        f32x4 acc0 = {0.f, 0.f, 0.f, 0.f}, acc1 = {0.f, 0.f, 0.f, 0.f};
        #pragma unroll
        for (int ks = 0; ks < 4; ++ks) {
            const f16x8 a = *(const f16x8*)&lds[(size_t)((ks * 6 + njh) * 64 + l) * 8];
            acc0 = MFMA16(a, xsB[0][ks], acc0);
            acc1 = MFMA16(a, xsB[1][ks], acc1);
        }
        const f32x4 bias = *(const f32x4*)(b0 + nj * 16 + g * 4);
        #pragma unroll
        for (int h = 0; h < 2; ++h) {
            const f32x4 acc = h ? acc1 : acc0;
            if (nj < 8) {
                float s[4];
                #pragma unroll
                for (int r = 0; r < 4; ++r) {
                    const float ys = acc[r] + bias[r];
                    s[r] = ys * __builtin_amdgcn_rcpf(1.0f + __expf(-ys)) * invCS;
                }
                xsS[h][nj >> 1].h2[2 * (nj & 1)]     += __builtin_amdgcn_cvt_pkrtz(s[0], s[1]);
                xsS[h][nj >> 1].h2[2 * (nj & 1) + 1] += __builtin_amdgcn_cvt_pkrtz(s[2], s[3]);
            } else {
                #pragma unroll
                for (int r = 0; r < 4; ++r) {
                    const float ys = acc[r] + bias[r];
                    gate[h][nj - 8][r] = fmaxf(ys, 0.f) * invCR;
                }
            }
        }
    }
}

// yv phase: gated residual update, w1 staged at lds.
__device__ __forceinline__ void yv_phase(
    Frag (&xvS)[2][3][2], const float (&gate)[2][4][4],
    const f16* lds, int l)
{
    f16x8 xvB[2][3][2];
    #pragma unroll
    for (int h = 0; h < 2; ++h)
        #pragma unroll
        for (int i = 0; i < 3; ++i)
            #pragma unroll
            for (int ks = 0; ks < 2; ++ks)
                xvB[h][i][ks] = xvS[h][i][ks].v;

    #pragma unroll
    for (int i = 0; i < 3; ++i)
        #pragma unroll
        for (int nj = 0; nj < 4; ++nj) {
            f32x4 acc0 = {0.f, 0.f, 0.f, 0.f}, acc1 = {0.f, 0.f, 0.f, 0.f};
            #pragma unroll
            for (int ks = 0; ks < 2; ++ks) {
                const f16x8 a = *(const f16x8*)&lds[(size_t)((ks * 4 + nj) * 64 + l) * 8];
                acc0 = MFMA16(a, xvB[0][i][ks], acc0);
                acc1 = MFMA16(a, xvB[1][i][ks], acc1);
            }
            #pragma unroll
            for (int h = 0; h < 2; ++h) {
                const f32x4 acc = h ? acc1 : acc0;
                float u[4];
                #pragma unroll
                for (int r = 0; r < 4; ++r)
                    u[r] = acc[r] * gate[h][nj][r];
                xvS[h][i][nj >> 1].h2[2 * (nj & 1)]     += __builtin_amdgcn_cvt_pkrtz(u[0], u[1]);
                xvS[h][i][nj >> 1].h2[2 * (nj & 1) + 1] += __builtin_amdgcn_cvt_pkrtz(u[2], u[3]);
            }
        }
}

// ---------------------------------------------------------------------------
__global__ __launch_bounds__(NTHR, 2)
void corrnet_lds(const float* __restrict__ x, const float* __restrict__ shift,
                 const float* __restrict__ oscale,
                 const float* __restrict__ b01, const float* __restrict__ b02,
                 const float* __restrict__ b0o,
                 const f16* __restrict__ wp, const float* __restrict__ consts,
                 float* __restrict__ out)
{
    __shared__ __align__(16) f16 smem[2048 * 8];   // 32 KB

    const int t = threadIdx.x;
    const int l = t & 63;
    const int w = __builtin_amdgcn_readfirstlane(t >> 6);  // 0..3
    const int g = l >> 4;
    const int c = l & 15;
    const size_t n0 = (size_t)blockIdx.x * 128 + (size_t)w * 32;

    const float invCS = consts[0], invCR = consts[1];
    const float inv_os = 1.0f / oscale[0];

    // ---- stage resblock1 pieceA: w01A (1536 units) + w11 (512 units) ----
    #pragma unroll
    for (int it = 0; it < 6; ++it) {
        const int u = it * NTHR + t;
        *(f16x8*)&smem[(size_t)u * 8] = *(const f16x8*)&wp[OFF_W01 + (size_t)u * 8];
    }
    #pragma unroll
    for (int it = 0; it < 2; ++it) {
        const int u = it * NTHR + t;
        *(f16x8*)&smem[LDS_W1 + (size_t)u * 8] = *(const f16x8*)&wp[OFF_W11 + (size_t)u * 8];
    }

    // ---- load 2 x-rows per lane -> packed f16 B-fragment state ----
    Frag xsS[2][4];
    Frag xvS[2][3][2];
    #pragma unroll
    for (int h = 0; h < 2; ++h) {
        const float* xrow = x + (n0 + h * 16 + c) * 320;
        #pragma unroll
        for (int ks = 0; ks < 4; ++ks) {
            const int col = ks * 32 + g * 4;
            const f32x4 t0 = *(const f32x4*)(xrow + col)      - *(const f32x4*)(shift + col);
            const f32x4 t1 = *(const f32x4*)(xrow + col + 16) - *(const f32x4*)(shift + col + 16);
            xsS[h][ks].v = packB(t0, t1);
        }
        f32x4 tmp[3][4];
        #pragma unroll
        for (int tau = 0; tau < 4; ++tau) {
            const int col = 128 + 3 * (tau * 16 + g * 4);
            const f32x4 a0 = *(const f32x4*)(xrow + col)     - *(const f32x4*)(shift + col);
            const f32x4 a1 = *(const f32x4*)(xrow + col + 4) - *(const f32x4*)(shift + col + 4);
            const f32x4 a2 = *(const f32x4*)(xrow + col + 8) - *(const f32x4*)(shift + col + 8);
            float arr[12];
            #pragma unroll
            for (int e = 0; e < 4; ++e) {
                arr[e] = a0[e]; arr[4 + e] = a1[e]; arr[8 + e] = a2[e];
            }
            #pragma unroll
            for (int r = 0; r < 4; ++r)
                #pragma unroll
                for (int i = 0; i < 3; ++i)
                    tmp[i][tau][r] = arr[3 * r + i];
        }
        #pragma unroll
        for (int i = 0; i < 3; ++i)
            #pragma unroll
            for (int ks = 0; ks < 2; ++ks)
                xvS[h][i][ks].v = packB(tmp[i][2 * ks], tmp[i][2 * ks + 1]);
    }

    float gate[2][4][4];

    // ================== resblock 1 ==================
    {
        f16x8 xsB[2][4];
        #pragma unroll
        for (int h = 0; h < 2; ++h)
            #pragma unroll
            for (int ks = 0; ks < 4; ++ks)
                xsB[h][ks] = xsS[h][ks].v;

        __syncthreads();   // pieceA + w11 staged
        ys_half(xsS, xsB, gate, smem, b01, 0, invCS, invCR, l, g);
        __syncthreads();   // pieceA reads done
        #pragma unroll
        for (int it = 0; it < 6; ++it) {   // stage pieceB over pieceA
            const int u = it * NTHR + t;
            *(f16x8*)&smem[(size_t)u * 8] = *(const f16x8*)&wp[OFF_W01 + 12288 + (size_t)u * 8];
        }
        __syncthreads();
        ys_half(xsS, xsB, gate, smem, b01, 6, invCS, invCR, l, g);
        yv_phase(xvS, gate, smem + LDS_W1, l);
        __syncthreads();   // all resblock1 reads done
    }

    // ---- stage resblock2 pieceA + w12 ----
    #pragma unroll
    for (int it = 0; it < 6; ++it) {
        const int u = it * NTHR + t;
        *(f16x8*)&smem[(size_t)u * 8] = *(const f16x8*)&wp[OFF_W02 + (size_t)u * 8];
    }
    #pragma unroll
    for (int it = 0; it < 2; ++it) {
        const int u = it * NTHR + t;
        *(f16x8*)&smem[LDS_W1 + (size_t)u * 8] = *(const f16x8*)&wp[OFF_W12 + (size_t)u * 8];
    }

    // ================== resblock 2 ==================
    {
        f16x8 xsB[2][4];
        #pragma unroll
        for (int h = 0; h < 2; ++h)
            #pragma unroll
            for (int ks = 0; ks < 4; ++ks)
                xsB[h][ks] = xsS[h][ks].v;

        __syncthreads();
        ys_half(xsS, xsB, gate, smem, b02, 0, invCS, invCR, l, g);
        __syncthreads();
        #pragma unroll
        for (int it = 0; it < 6; ++it) {
            const int u = it * NTHR + t;
            *(f16x8*)&smem[(size_t)u * 8] = *(const f16x8*)&wp[OFF_W02 + 12288 + (size_t)u * 8];
        }
        __syncthreads();
        ys_half(xsS, xsB, gate, smem, b02, 6, invCS, invCR, l, g);
        yv_phase(xvS, gate, smem + LDS_W1, l);
        __syncthreads();
    }

    // ---- stage head H1: w0o (1024 units) at 0, tp0 (512 units) at f16 8192 ----
    #pragma unroll
    for (int it = 0; it < 4; ++it) {
        const int u = it * NTHR + t;
        *(f16x8*)&smem[(size_t)u * 8] = *(const f16x8*)&wp[OFF_W0O + (size_t)u * 8];
    }
    #pragma unroll
    for (int it = 0; it < 2; ++it) {
        const int u = it * NTHR + t;
        *(f16x8*)&smem[8192 + (size_t)u * 8] = *(const f16x8*)&wp[OFF_TP0 + (size_t)u * 8];
    }
    __syncthreads();

    // ---- zs = xs @ w0o + b0o ----
    f32x4 zs[2][4];
    #pragma unroll
    for (int nj = 0; nj < 4; ++nj) {
        f32x4 acc0 = {0.f, 0.f, 0.f, 0.f}, acc1 = {0.f, 0.f, 0.f, 0.f};
        #pragma unroll
        for (int ks = 0; ks < 4; ++ks) {
            const f16x8 a = *(const f16x8*)&smem[(size_t)((ks * 4 + nj) * 64 + l) * 8];
            acc0 = MFMA16(a, xsS[0][ks].v, acc0);
            acc1 = MFMA16(a, xsS[1][ks].v, acc1);
        }
        const f32x4 bias = *(const f32x4*)(b0o + nj * 16 + g * 4);
        #pragma unroll
        for (int r = 0; r < 4; ++r) {
            zs[0][nj][r] = acc0[r] + bias[r];
            zs[1][nj][r] = acc1[r] + bias[r];
        }
    }

    float part[2]  = {0.f, 0.f};
    float part1[2] = {0.f, 0.f};

    // ---- y0: zs @ TP0 . zs (tp0 at f16 8192) ----
    {
        f16x8 zsB[2][2];
        #pragma unroll
        for (int h = 0; h < 2; ++h)
            #pragma unroll
            for (int ks = 0; ks < 2; ++ks)
                zsB[h][ks] = packB(zs[h][2 * ks], zs[h][2 * ks + 1]);
        #pragma unroll
        for (int nj = 0; nj < 4; ++nj) {
            f32x4 acc0 = {0.f, 0.f, 0.f, 0.f}, acc1 = {0.f, 0.f, 0.f, 0.f};
            #pragma unroll
            for (int ks = 0; ks < 2; ++ks) {
                const f16x8 a = *(const f16x8*)&smem[8192 + (size_t)((ks * 4 + nj) * 64 + l) * 8];
                acc0 = MFMA16(a, zsB[0][ks], acc0);
                acc1 = MFMA16(a, zsB[1][ks], acc1);
            }
            #pragma unroll
            for (int r = 0; r < 4; ++r) {
                part[0] += acc0[r] * zs[0][nj][r];
                part[1] += acc1[r] * zs[1][nj][r];
            }
        }
    }
    __syncthreads();   // H1 reads done

    // ---- stage head H2: w1o (512) at 0, tp1 (512) at f16 4096 ----
    #pragma unroll
    for (int it = 0; it < 2; ++it) {
        const int u = it * NTHR + t;
        *(f16x8*)&smem[(size_t)u * 8] = *(const f16x8*)&wp[OFF_W1O + (size_t)u * 8];
    }
    #pragma unroll
    for (int it = 0; it < 2; ++it) {
        const int u = it * NTHR + t;
        *(f16x8*)&smem[4096 + (size_t)u * 8] = *(const f16x8*)&wp[OFF_TP1 + (size_t)u * 8];
    }
    __syncthreads();

    // ---- y1: per i, zv = xv_i @ w1o ; zv @ TP1 . zv ----
    #pragma unroll
    for (int i = 0; i < 3; ++i) {
        f32x4 zv[2][4];
        #pragma unroll
        for (int nj = 0; nj < 4; ++nj) {
            f32x4 acc0 = {0.f, 0.f, 0.f, 0.f}, acc1 = {0.f, 0.f, 0.f, 0.f};
            #pragma unroll
            for (int ks = 0; ks < 2; ++ks) {
                const f16x8 a = *(const f16x8*)&smem[(size_t)((ks * 4 + nj) * 64 + l) * 8];
                acc0 = MFMA16(a, xvS[0][i][ks].v, acc0);
                acc1 = MFMA16(a, xvS[1][i][ks].v, acc1);
            }
            #pragma unroll
            for (int r = 0; r < 4; ++r) {
                zv[0][nj][r] = acc0[r];
                zv[1][nj][r] = acc1[r];
            }
        }
        f16x8 zvB[2][2];
        #pragma unroll
        for (int h = 0; h < 2; ++h)
            #pragma unroll
            for (int ks = 0; ks < 2; ++ks)
                zvB[h][ks] = packB(zv[h][2 * ks], zv[h][2 * ks + 1]);
        #pragma unroll
        for (int nj = 0; nj < 4; ++nj) {
            f32x4 acc0 = {0.f, 0.f, 0.f, 0.f}, acc1 = {0.f, 0.f, 0.f, 0.f};
            #pragma unroll
            for (int ks = 0; ks < 2; ++ks) {
                const f16x8 a = *(const f16x8*)&smem[4096 + (size_t)((ks * 4 + nj) * 64 + l) * 8];
                acc0 = MFMA16(a, zvB[0][ks], acc0);
                acc1 = MFMA16(a, zvB[1][ks], acc1);
            }
            #pragma unroll
            for (int r = 0; r < 4; ++r) {
                part1[0] += acc0[r] * zv[0][nj][r];
                part1[1] += acc1[r] * zv[1][nj][r];
            }
        }
    }
    #pragma unroll
    for (int h = 0; h < 2; ++h)
        part[h] += part1[h];

    #pragma unroll
    for (int h = 0; h < 2; ++h) {
        part[h] += __shfl_xor(part[h], 16, 64);
        part[h] += __shfl_xor(part[h], 32, 64);
    }

    if (l < 16)
        out[n0 + l] = part[0] * TP_NORM * inv_os;
    else if (l < 32)
        out[n0 + 16 + (l - 16)] = part[1] * TP_NORM * inv_os;
}

// ---------------------------------------------------------------------------
extern "C" void kernel_launch(void* const* d_in, const int* in_sizes, int n_in,
                              void* d_out, int out_size, void* d_ws, size_t ws_size,
                              hipStream_t stream) {
    const float* x      = (const float*)d_in[0];
    const float* shift  = (const float*)d_in[1];
    const float* oscale = (const float*)d_in[2];
    const float* w01    = (const float*)d_in[3];
    const float* b01    = (const float*)d_in[4];
    const float* w11    = (const float*)d_in[5];
    const float* w02    = (const float*)d_in[6];
    const float* b02    = (const float*)d_in[7];
    const float* w12    = (const float*)d_in[8];
    const float* w0o    = (const float*)d_in[9];
    const float* b0o    = (const float*)d_in[10];
    const float* w1o    = (const float*)d_in[11];
    const float* wtp0   = (const float*)d_in[12];
    const float* wtp1   = (const float*)d_in[13];
    float* out    = (float*)d_out;
    float* consts = (float*)d_ws;
    f16*   wp     = (f16*)((char*)d_ws + 16);

    init_consts_kernel<<<1, 256, 0, stream>>>(consts);
    pack_weights<<<(PACK_UNITS + 255) / 256, 256, 0, stream>>>(
        w01, w11, w02, w12, w0o, w1o, wtp0, wtp1, wp);

    const int nblocks = 131072 / 128;  // 1024
    corrnet_lds<<<nblocks, NTHR, 0, stream>>>(
        x, shift, oscale, b01, b02, b0o, wp, consts, out);
}

// Round 12
// 75.654 us; speedup vs baseline: 1.3227x; 1.3227x over previous
//
#include <hip/hip_runtime.h>
#include <math.h>

// CorrNet fused MFMA-f16 kernel, v9: R9 base + fast consts + LDS-staged biases.
// M=128, K=64, T=64, N=131072, D_IN=320.
// 512-thread blocks (8 waves x 32 samples). Weights AND biases pre-packed in
// d_ws; staged into ~58KB LDS in 3 chunks; all fragment + bias reads are
// ds_read_b128. State in registers (phi-permuted packed f16 B-fragments,
// in-lane cvt_pkrtz updates). init_consts parallelized (1024 thr, ~2us).

typedef _Float16 f16;
typedef _Float16 f16x8 __attribute__((ext_vector_type(8)));
typedef __fp16   fp16x2 __attribute__((ext_vector_type(2)));
typedef float    f32x4 __attribute__((ext_vector_type(4)));
typedef int      i32x4 __attribute__((ext_vector_type(4)));

#define MFMA16(a, b, c) __builtin_amdgcn_mfma_f32_16x16x32_f16(a, b, c, 0, 0, 0)

constexpr float INV_SQRT_M = 0.08838834764831845f;   // 1/sqrt(128)
constexpr float INV_SQRT_K = 0.125f;                 // 1/sqrt(64)
constexpr float INV_SQRT_3 = 0.57735026918962576f;
constexpr float TP_NORM    = 0.011048543456039806f;  // 1/sqrt(2*64*64)

// packed-weight segment offsets in f16 units (base = d_ws + 16 bytes)
// chunk0 = [0, 28672)        : w01 (24576) || w11 (4096); bias b01 after
// chunk1 = [28672, 57344)    : w02 (24576) || w12 (4096); bias b02 after
// chunk2 = [57344, 77824)    : w0o(8192)||w1o(4096)||tp0(4096)||tp1(4096); b0o
#define OFF_W01 0
#define OFF_W11 24576
#define OFF_W02 28672
#define OFF_W12 53248
#define OFF_W0O 57344
#define OFF_W1O 65536
#define OFF_TP0 69632
#define OFF_TP1 73728
#define PACK_UNITS 9728   // f16x8 weight units
// bias storage (float units, relative to wp base)
#define FB01 38912        // 192 floats
#define FB02 39104        // 192 floats
#define FB0O 39296        // 64 floats
#define TOTAL_UNITS (PACK_UNITS + 448)

// in-LDS offsets
#define LDS_W1     24576  // f16 units: w1 within resblock chunk
#define LDS_BIAS_F 14336  // float units: bias after 28672 f16 weights
#define LDS_W0O    0      // head chunk (f16 units)
#define LDS_W1O    8192
#define LDS_TP0    12288
#define LDS_TP1    16384
#define LDS_B0O_F  10240  // float units: b0o after 20480 f16 head weights

#define NTHR 512

// ---------------------------------------------------------------------------
// consts: replicate numpy trapz for C_SILU / C_RELU in fp64 (parallel, ~2us).
// ws[0] = 1/C_SILU, ws[1] = 1/C_RELU.
// ---------------------------------------------------------------------------
__global__ void init_consts_kernel(float* __restrict__ ws) {
    __shared__ double red[1024];
    const int t = threadIdx.x;
    double acc_s = 0.0, acc_r = 0.0;
    for (int i = t; i <= 20000; i += 1024) {
        const double z = -8.0 + (16.0 * (double)i) / 20000.0;
        const double pdf = exp(-0.5 * z * z) / 2.5066282746310002;
        const double sil = z / (1.0 + exp(-z));
        const double wgt = (i == 0 || i == 20000) ? 0.5 : 1.0;
        acc_s += wgt * sil * sil * pdf;
        if (z > 0.0) acc_r += wgt * z * z * pdf;
    }
    red[t] = acc_s;
    __syncthreads();
    for (int o = 512; o > 0; o >>= 1) { if (t < o) red[t] += red[t + o]; __syncthreads(); }
    const double tot_s = red[0];
    __syncthreads();
    red[t] = acc_r;
    __syncthreads();
    for (int o = 512; o > 0; o >>= 1) { if (t < o) red[t] += red[t + o]; __syncthreads(); }
    if (t == 0) {
        const double dz = 16.0 / 20000.0;
        ws[0] = (float)(1.0 / sqrt(tot_s * dz));
        ws[1] = (float)(1.0 / sqrt(red[0] * dz));
    }
}

// ---------------------------------------------------------------------------
// Pack weights fp32 -> f16 A-fragments of W^T, phi-permuted k-rows, scales
// folded (w0*: 1/sqrt(M); w1*: 1/sqrt(K); tp1: 1/sqrt(3); tp0: 1).
// Also copies raw f32 biases to the tail of the buffer.
// ---------------------------------------------------------------------------
__global__ void pack_weights(const float* __restrict__ w01, const float* __restrict__ w11,
                             const float* __restrict__ w02, const float* __restrict__ w12,
                             const float* __restrict__ w0o, const float* __restrict__ w1o,
                             const float* __restrict__ tp0, const float* __restrict__ tp1,
                             const float* __restrict__ b01, const float* __restrict__ b02,
                             const float* __restrict__ b0o,
                             f16* __restrict__ dst) {
    int u = blockIdx.x * 256 + threadIdx.x;
    if (u >= TOTAL_UNITS) return;
    if (u >= PACK_UNITS) {                // bias copy
        const int idx = u - PACK_UNITS;   // 0..447
        float* dstF = (float*)dst;
        if (idx < 192)      dstF[FB01 + idx] = b01[idx];
        else if (idx < 384) dstF[FB02 + (idx - 192)] = b02[idx - 192];
        else                dstF[FB0O + (idx - 384)] = b0o[idx - 384];
        return;
    }
    const float* src; int NC, base, lu = u; float sc;
    if      (lu < 3072) {            src = w01; NC = 192; base = OFF_W01; sc = INV_SQRT_M; }
    else if (lu < 3584) { lu -= 3072; src = w11; NC = 64;  base = OFF_W11; sc = INV_SQRT_K; }
    else if (lu < 6656) { lu -= 3584; src = w02; NC = 192; base = OFF_W02; sc = INV_SQRT_M; }
    else if (lu < 7168) { lu -= 6656; src = w12; NC = 64;  base = OFF_W12; sc = INV_SQRT_K; }
    else if (lu < 8192) { lu -= 7168; src = w0o; NC = 64;  base = OFF_W0O; sc = INV_SQRT_M; }
    else if (lu < 8704) { lu -= 8192; src = w1o; NC = 64;  base = OFF_W1O; sc = INV_SQRT_K; }
    else if (lu < 9216) { lu -= 8704; src = tp0; NC = 64;  base = OFF_TP0; sc = 1.0f; }
    else                { lu -= 9216; src = tp1; NC = 64;  base = OFF_TP1; sc = INV_SQRT_3; }
    const int lane = lu & 63;
    const int frag = lu >> 6;          // kstep*NT + nj
    const int NT = NC >> 4;
    const int kstep = frag / NT, nj = frag - kstep * NT;
    const int gl  = lane >> 4;
    const int col = nj * 16 + (lane & 15);
    f16 tmp[8];
    #pragma unroll
    for (int e = 0; e < 8; ++e) {
        const int row = kstep * 32 + ((e >> 2) << 4) + (gl << 2) + (e & 3);  // phi
        tmp[e] = (f16)(src[(size_t)row * NC + col] * sc);
    }
    *(f16x8*)&dst[(size_t)(base) + (size_t)lu * 8] = *(f16x8*)tmp;
}

// ---------------------------------------------------------------------------
__device__ __forceinline__ int pk2i(float a, float b) {
    union { fp16x2 h; int i; } u;
    u.h = __builtin_amdgcn_cvt_pkrtz(a, b);
    return u.i;
}

// B-fragment from two D-layout f32 tiles (phi-relabeled, pure in-lane).
__device__ __forceinline__ f16x8 packB(f32x4 t0, f32x4 t1) {
    union { i32x4 i; f16x8 v; } u;
    u.i[0] = pk2i(t0[0], t0[1]);
    u.i[1] = pk2i(t0[2], t0[3]);
    u.i[2] = pk2i(t1[0], t1[1]);
    u.i[3] = pk2i(t1[2], t1[3]);
    return u.v;
}

union Frag { f16x8 v; fp16x2 h2[4]; };

// ---------------------------------------------------------------------------
// One residual block; weights + biases from LDS (w0 at lds+0, w1 at LDS_W1,
// bias f32 at LDS_BIAS_F). Scales pre-folded: ys = acc + bias; dxv = acc*gate.
// ---------------------------------------------------------------------------
__device__ __forceinline__ void resblock32(
    Frag (&xsS)[2][4], Frag (&xvS)[2][3][2],
    const f16* lds, float invCS, float invCR, int l, int g)
{
    const float* biasF = (const float*)lds + LDS_BIAS_F;

    // snapshot xs B-operands (pre-update values for the whole GEMM)
    f16x8 xsB[2][4];
    #pragma unroll
    for (int h = 0; h < 2; ++h)
        #pragma unroll
        for (int ks = 0; ks < 4; ++ks)
            xsB[h][ks] = xsS[h][ks].v;

    float gate[2][4][4];
    // ys^T = W0^T @ xs^T : 12 row-tiles of 16 output features
    #pragma unroll
    for (int nj = 0; nj < 12; ++nj) {
        f32x4 acc0 = {0.f, 0.f, 0.f, 0.f}, acc1 = {0.f, 0.f, 0.f, 0.f};
        #pragma unroll
        for (int ks = 0; ks < 4; ++ks) {
            const f16x8 a = *(const f16x8*)&lds[(size_t)((ks * 12 + nj) * 64 + l) * 8];
            acc0 = MFMA16(a, xsB[0][ks], acc0);
            acc1 = MFMA16(a, xsB[1][ks], acc1);
        }
        const f32x4 bias = *(const f32x4*)&biasF[nj * 16 + g * 4];
        #pragma unroll
        for (int h = 0; h < 2; ++h) {
            const f32x4 acc = h ? acc1 : acc0;
            if (nj < 8) {
                float s[4];
                #pragma unroll
                for (int r = 0; r < 4; ++r) {
                    const float ys = acc[r] + bias[r];
                    s[r] = ys * __builtin_amdgcn_rcpf(1.0f + __expf(-ys)) * invCS;
                }
                xsS[h][nj >> 1].h2[2 * (nj & 1)]     += __builtin_amdgcn_cvt_pkrtz(s[0], s[1]);
                xsS[h][nj >> 1].h2[2 * (nj & 1) + 1] += __builtin_amdgcn_cvt_pkrtz(s[2], s[3]);
            } else {
                #pragma unroll
                for (int r = 0; r < 4; ++r) {
                    const float ys = acc[r] + bias[r];
                    gate[h][nj - 8][r] = fmaxf(ys, 0.f) * invCR;
                }
            }
        }
    }

    // snapshot xv B-operands
    f16x8 xvB[2][3][2];
    #pragma unroll
    for (int h = 0; h < 2; ++h)
        #pragma unroll
        for (int i = 0; i < 3; ++i)
            #pragma unroll
            for (int ks = 0; ks < 2; ++ks)
                xvB[h][i][ks] = xvS[h][i][ks].v;

    // yv^T per i, gated residual update
    #pragma unroll
    for (int i = 0; i < 3; ++i)
        #pragma unroll
        for (int nj = 0; nj < 4; ++nj) {
            f32x4 acc0 = {0.f, 0.f, 0.f, 0.f}, acc1 = {0.f, 0.f, 0.f, 0.f};
            #pragma unroll
            for (int ks = 0; ks < 2; ++ks) {
                const f16x8 a = *(const f16x8*)&lds[LDS_W1 + (size_t)((ks * 4 + nj) * 64 + l) * 8];
                acc0 = MFMA16(a, xvB[0][i][ks], acc0);
                acc1 = MFMA16(a, xvB[1][i][ks], acc1);
            }
            #pragma unroll
            for (int h = 0; h < 2; ++h) {
                const f32x4 acc = h ? acc1 : acc0;
                float u[4];
                #pragma unroll
                for (int r = 0; r < 4; ++r)
                    u[r] = acc[r] * gate[h][nj][r];
                xvS[h][i][nj >> 1].h2[2 * (nj & 1)]     += __builtin_amdgcn_cvt_pkrtz(u[0], u[1]);
                xvS[h][i][nj >> 1].h2[2 * (nj & 1) + 1] += __builtin_amdgcn_cvt_pkrtz(u[2], u[3]);
            }
        }
}

// ---------------------------------------------------------------------------
__global__ __launch_bounds__(NTHR, 2)
void corrnet_lds(const float* __restrict__ x, const float* __restrict__ shift,
                 const float* __restrict__ oscale,
                 const f16* __restrict__ wp, const float* __restrict__ consts,
                 float* __restrict__ out)
{
    __shared__ __align__(16) f16 smem[29056];   // 58,112 B
    float* smemF = (float*)smem;
    const float* wpF = (const float*)wp;

    const int t = threadIdx.x;
    const int l = t & 63;
    const int w = __builtin_amdgcn_readfirstlane(t >> 6);  // 0..7
    const int g = l >> 4;
    const int c = l & 15;
    const size_t n0 = (size_t)blockIdx.x * 256 + (size_t)w * 32;

    const float invCS = consts[0], invCR = consts[1];
    const float inv_os = 1.0f / oscale[0];

    // ---- stage chunk0 (w01 || w11 || b01): 3584 units / 512 thr = 7 each ----
    #pragma unroll
    for (int it = 0; it < 7; ++it) {
        const int u = it * NTHR + t;
        *(f16x8*)&smem[(size_t)u * 8] = *(const f16x8*)&wp[(size_t)u * 8];
    }
    if (t < 48)
        ((f32x4*)&smemF[LDS_BIAS_F])[t] = ((const f32x4*)&wpF[FB01])[t];

    // ---- load 2 x-rows per lane -> packed f16 B-fragment state ----
    Frag xsS[2][4];
    Frag xvS[2][3][2];
    #pragma unroll
    for (int h = 0; h < 2; ++h) {
        const float* xrow = x + (n0 + h * 16 + c) * 320;
        #pragma unroll
        for (int ks = 0; ks < 4; ++ks) {
            const int col = ks * 32 + g * 4;
            const f32x4 t0 = *(const f32x4*)(xrow + col)      - *(const f32x4*)(shift + col);
            const f32x4 t1 = *(const f32x4*)(xrow + col + 16) - *(const f32x4*)(shift + col + 16);
            xsS[h][ks].v = packB(t0, t1);
        }
        f32x4 tmp[3][4];
        #pragma unroll
        for (int tau = 0; tau < 4; ++tau) {
            const int col = 128 + 3 * (tau * 16 + g * 4);
            const f32x4 a0 = *(const f32x4*)(xrow + col)     - *(const f32x4*)(shift + col);
            const f32x4 a1 = *(const f32x4*)(xrow + col + 4) - *(const f32x4*)(shift + col + 4);
            const f32x4 a2 = *(const f32x4*)(xrow + col + 8) - *(const f32x4*)(shift + col + 8);
            float arr[12];
            #pragma unroll
            for (int e = 0; e < 4; ++e) {
                arr[e] = a0[e]; arr[4 + e] = a1[e]; arr[8 + e] = a2[e];
            }
            #pragma unroll
            for (int r = 0; r < 4; ++r)
                #pragma unroll
                for (int i = 0; i < 3; ++i)
                    tmp[i][tau][r] = arr[3 * r + i];
        }
        #pragma unroll
        for (int i = 0; i < 3; ++i)
            #pragma unroll
            for (int ks = 0; ks < 2; ++ks)
                xvS[h][i][ks].v = packB(tmp[i][2 * ks], tmp[i][2 * ks + 1]);
    }

    __syncthreads();                       // chunk0 staged
    resblock32(xsS, xvS, smem, invCS, invCR, l, g);
    __syncthreads();                       // all reads of chunk0 done

    // ---- stage chunk1 (w02 || w12 || b02) ----
    #pragma unroll
    for (int it = 0; it < 7; ++it) {
        const int u = it * NTHR + t;
        *(f16x8*)&smem[(size_t)u * 8] = *(const f16x8*)&wp[(size_t)(OFF_W02) + (size_t)u * 8];
    }
    if (t < 48)
        ((f32x4*)&smemF[LDS_BIAS_F])[t] = ((const f32x4*)&wpF[FB02])[t];
    __syncthreads();
    resblock32(xsS, xvS, smem, invCS, invCR, l, g);
    __syncthreads();

    // ---- stage chunk2 (w0o || w1o || tp0 || tp1 || b0o): 2560 units ----
    #pragma unroll
    for (int it = 0; it < 5; ++it) {
        const int u = it * NTHR + t;
        *(f16x8*)&smem[(size_t)u * 8] = *(const f16x8*)&wp[(size_t)(OFF_W0O) + (size_t)u * 8];
    }
    if (t < 16)
        ((f32x4*)&smemF[LDS_B0O_F])[t] = ((const f32x4*)&wpF[FB0O])[t];
    __syncthreads();

    // ---- output head: zs (w0o pre-scaled, bias from LDS) ----
    f32x4 zs[2][4];
    #pragma unroll
    for (int nj = 0; nj < 4; ++nj) {
        f32x4 acc0 = {0.f, 0.f, 0.f, 0.f}, acc1 = {0.f, 0.f, 0.f, 0.f};
        #pragma unroll
        for (int ks = 0; ks < 4; ++ks) {
            const f16x8 a = *(const f16x8*)&smem[LDS_W0O + (size_t)((ks * 4 + nj) * 64 + l) * 8];
            acc0 = MFMA16(a, xsS[0][ks].v, acc0);
            acc1 = MFMA16(a, xsS[1][ks].v, acc1);
        }
        const f32x4 bias = *(const f32x4*)&smemF[LDS_B0O_F + nj * 16 + g * 4];
        #pragma unroll
        for (int r = 0; r < 4; ++r) {
            zs[0][nj][r] = acc0[r] + bias[r];
            zs[1][nj][r] = acc1[r] + bias[r];
        }
    }

    float part[2]  = {0.f, 0.f};
    float part1[2] = {0.f, 0.f};

    // ---- y0: zs @ TP0 . zs ----
    {
        f16x8 zsB[2][2];
        #pragma unroll
        for (int h = 0; h < 2; ++h)
            #pragma unroll
            for (int ks = 0; ks < 2; ++ks)
                zsB[h][ks] = packB(zs[h][2 * ks], zs[h][2 * ks + 1]);
        #pragma unroll
        for (int nj = 0; nj < 4; ++nj) {
            f32x4 acc0 = {0.f, 0.f, 0.f, 0.f}, acc1 = {0.f, 0.f, 0.f, 0.f};
            #pragma unroll
            for (int ks = 0; ks < 2; ++ks) {
                const f16x8 a = *(const f16x8*)&smem[LDS_TP0 + (size_t)((ks * 4 + nj) * 64 + l) * 8];
                acc0 = MFMA16(a, zsB[0][ks], acc0);
                acc1 = MFMA16(a, zsB[1][ks], acc1);
            }
            #pragma unroll
            for (int r = 0; r < 4; ++r) {
                part[0] += acc0[r] * zs[0][nj][r];
                part[1] += acc1[r] * zs[1][nj][r];
            }
        }
    }

    // ---- y1: per i, zv = xv_i @ w1o ; zv @ TP1 . zv (tp1 pre-scaled) ----
    #pragma unroll
    for (int i = 0; i < 3; ++i) {
        f32x4 zv[2][4];
        #pragma unroll
        for (int nj = 0; nj < 4; ++nj) {
            f32x4 acc0 = {0.f, 0.f, 0.f, 0.f}, acc1 = {0.f, 0.f, 0.f, 0.f};
            #pragma unroll
            for (int ks = 0; ks < 2; ++ks) {
                const f16x8 a = *(const f16x8*)&smem[LDS_W1O + (size_t)((ks * 4 + nj) * 64 + l) * 8];
                acc0 = MFMA16(a, xvS[0][i][ks].v, acc0);
                acc1 = MFMA16(a, xvS[1][i][ks].v, acc1);
            }
            #pragma unroll
            for (int r = 0; r < 4; ++r) {
                zv[0][nj][r] = acc0[r];
                zv[1][nj][r] = acc1[r];
            }
        }
        f16x8 zvB[2][2];
        #pragma unroll
        for (int h = 0; h < 2; ++h)
            #pragma unroll
            for (int ks = 0; ks < 2; ++ks)
                zvB[h][ks] = packB(zv[h][2 * ks], zv[h][2 * ks + 1]);
        #pragma unroll
        for (int nj = 0; nj < 4; ++nj) {
            f32x4 acc0 = {0.f, 0.f, 0.f, 0.f}, acc1 = {0.f, 0.f, 0.f, 0.f};
            #pragma unroll
            for (int ks = 0; ks < 2; ++ks) {
                const f16x8 a = *(const f16x8*)&smem[LDS_TP1 + (size_t)((ks * 4 + nj) * 64 + l) * 8];
                acc0 = MFMA16(a, zvB[0][ks], acc0);
                acc1 = MFMA16(a, zvB[1][ks], acc1);
            }
            #pragma unroll
            for (int r = 0; r < 4; ++r) {
                part1[0] += acc0[r] * zv[0][nj][r];
                part1[1] += acc1[r] * zv[1][nj][r];
            }
        }
    }
    #pragma unroll
    for (int h = 0; h < 2; ++h)
        part[h] += part1[h];

    // reduce over the 4 g-groups (features) -> per-sample totals
    #pragma unroll
    for (int h = 0; h < 2; ++h) {
        part[h] += __shfl_xor(part[h], 16, 64);
        part[h] += __shfl_xor(part[h], 32, 64);
    }

    if (l < 16)
        out[n0 + l] = part[0] * TP_NORM * inv_os;
    else if (l < 32)
        out[n0 + 16 + (l - 16)] = part[1] * TP_NORM * inv_os;
}

// ---------------------------------------------------------------------------
extern "C" void kernel_launch(void* const* d_in, const int* in_sizes, int n_in,
                              void* d_out, int out_size, void* d_ws, size_t ws_size,
                              hipStream_t stream) {
    const float* x      = (const float*)d_in[0];
    const float* shift  = (const float*)d_in[1];
    const float* oscale = (const float*)d_in[2];
    const float* w01    = (const float*)d_in[3];
    const float* b01    = (const float*)d_in[4];
    const float* w11    = (const float*)d_in[5];
    const float* w02    = (const float*)d_in[6];
    const float* b02    = (const float*)d_in[7];
    const float* w12    = (const float*)d_in[8];
    const float* w0o    = (const float*)d_in[9];
    const float* b0o    = (const float*)d_in[10];
    const float* w1o    = (const float*)d_in[11];
    const float* wtp0   = (const float*)d_in[12];
    const float* wtp1   = (const float*)d_in[13];
    float* out    = (float*)d_out;
    float* consts = (float*)d_ws;
    f16*   wp     = (f16*)((char*)d_ws + 16);

    init_consts_kernel<<<1, 1024, 0, stream>>>(consts);
    pack_weights<<<(TOTAL_UNITS + 255) / 256, 256, 0, stream>>>(
        w01, w11, w02, w12, w0o, w1o, wtp0, wtp1, b01, b02, b0o, wp);

    const int nblocks = 131072 / 256;  // 512
    corrnet_lds<<<nblocks, NTHR, 0, stream>>>(
        x, shift, oscale, wp, consts, out);
}